// Round 3
// baseline (930.383 us; speedup 1.0000x reference)
//
#include <hip/hip_runtime.h>
#include <math.h>

#define C   128
#define BLK 1024
#define WPB (BLK / 64)   // 16 waves per block

__device__ __forceinline__ float4 f4add(float4 a, float4 b) {
    float4 r; r.x = a.x + b.x; r.y = a.y + b.y; r.z = a.z + b.z; r.w = a.w + b.w; return r;
}
__device__ __forceinline__ float4 f4shfl_xor(float4 v, int m) {
    float4 r;
    r.x = __shfl_xor(v.x, m, 64);
    r.y = __shfl_xor(v.y, m, 64);
    r.z = __shfl_xor(v.z, m, 64);
    r.w = __shfl_xor(v.w, m, 64);
    return r;
}

extern "C" __global__ __launch_bounds__(BLK)
void cba_wave_kernel(const float* __restrict__ x,
                     const float* __restrict__ W,
                     const int* __restrict__ batch,
                     float* __restrict__ out,
                     int N, int B, int totalWaves)
{
    __shared__ float4 sW4[C * C / 4];   // 64 KB, rows k, float4 over cols

    const int t    = threadIdx.x;
    const int lane = t & 63;
    const int q    = lane & 31;   // owns channels/cols 4q..4q+3
    const int h    = lane >> 5;   // half 0/1

    // ---- one-time: W into LDS (coalesced float4) ----
    const float4* Wg = (const float4*)W;
#pragma unroll
    for (int i = 0; i < (C * C / 4) / BLK; ++i)
        sW4[t + i * BLK] = Wg[t + i * BLK];
    __syncthreads();

    const int gw = blockIdx.x * WPB + (t >> 6);       // global wave id

    // ---- chunk-contiguous segment assignment: wave owns [segStart, segStart+myCnt) ----
    const int qn = B / totalWaves;
    const int r  = B % totalWaves;
    const int segStart = gw * qn + (gw < r ? gw : r);
    const int myCnt    = qn + (gw < r ? 1 : 0);

    // ---- lane-parallel boundary search: lane l finds start of segment segStart+min(l,myCnt) ----
    {
        const int tl = lane < myCnt ? lane : myCnt;
        const int target = segStart + tl;
        int lo = 0, hi = N;
        while (lo < hi) {
            int mid = (lo + hi) >> 1;
            if (batch[mid] < target) lo = mid + 1; else hi = mid;
        }
        // fallthrough: bs in register
        const int bs = lo;
        const float4* x4 = (const float4*)x;

        for (int k = 0; k < myCnt; ++k) {
            const int b = segStart + k;
            const int s = __shfl(bs, k, 64);
            const int e = __shfl(bs, k + 1, 64);

            // ======== pass 1: channel sums, 4 independent load chains (8 rows/iter) ========
            float4 a0 = {0.f,0.f,0.f,0.f}, a1 = a0, a2 = a0, a3 = a0;
            int i = s + h;
            for (; i + 6 < e; i += 8) {
                float4 v0 = x4[(size_t)(i + 0) * 32 + q];
                float4 v1 = x4[(size_t)(i + 2) * 32 + q];
                float4 v2 = x4[(size_t)(i + 4) * 32 + q];
                float4 v3 = x4[(size_t)(i + 6) * 32 + q];
                a0 = f4add(a0, v0); a1 = f4add(a1, v1);
                a2 = f4add(a2, v2); a3 = f4add(a3, v3);
            }
            for (; i < e; i += 2)
                a0 = f4add(a0, x4[(size_t)i * 32 + q]);
            float4 acc = f4add(f4add(a0, a1), f4add(a2, a3));
            acc = f4add(acc, f4shfl_xor(acc, 32));
            const float inv = 1.0f / (float)((e - s) > 0 ? (e - s) : 1);
            float4 mean;
            mean.x = acc.x * inv; mean.y = acc.y * inv;
            mean.z = acc.z * inv; mean.w = acc.w * inv;

            // ======== GEMM: c = tanh(mean @ W), split-K across the two halves ========
            float4 p = {0.f,0.f,0.f,0.f};
#pragma unroll
            for (int j = 0; j < 16; ++j) {
                const int src = (h << 4) + j;
                const float mx = __shfl(mean.x, src, 64);
                const float my = __shfl(mean.y, src, 64);
                const float mz = __shfl(mean.z, src, 64);
                const float mw = __shfl(mean.w, src, 64);
                const int k0 = (h << 6) + (j << 2);
                const float4 w0 = sW4[(k0 + 0) * 32 + q];
                const float4 w1 = sW4[(k0 + 1) * 32 + q];
                const float4 w2 = sW4[(k0 + 2) * 32 + q];
                const float4 w3 = sW4[(k0 + 3) * 32 + q];
                p.x = fmaf(mx, w0.x, p.x); p.y = fmaf(mx, w0.y, p.y);
                p.z = fmaf(mx, w0.z, p.z); p.w = fmaf(mx, w0.w, p.w);
                p.x = fmaf(my, w1.x, p.x); p.y = fmaf(my, w1.y, p.y);
                p.z = fmaf(my, w1.z, p.z); p.w = fmaf(my, w1.w, p.w);
                p.x = fmaf(mz, w2.x, p.x); p.y = fmaf(mz, w2.y, p.y);
                p.z = fmaf(mz, w2.z, p.z); p.w = fmaf(mz, w2.w, p.w);
                p.x = fmaf(mw, w3.x, p.x); p.y = fmaf(mw, w3.y, p.y);
                p.z = fmaf(mw, w3.z, p.z); p.w = fmaf(mw, w3.w, p.w);
            }
            p = f4add(p, f4shfl_xor(p, 32));
            float4 cv;
            cv.x = tanhf(p.x); cv.y = tanhf(p.y);
            cv.z = tanhf(p.z); cv.w = tanhf(p.w);

            // ======== pass 2: gate+accumulate, 4 independent chains (8 rows/iter) ========
            float4 h0 = {0.f,0.f,0.f,0.f}, h1 = h0, h2 = h0, h3 = h0;
            i = s + h;
            for (; i + 6 < e; i += 8) {
                float4 v0 = x4[(size_t)(i + 0) * 32 + q];
                float4 v1 = x4[(size_t)(i + 2) * 32 + q];
                float4 v2 = x4[(size_t)(i + 4) * 32 + q];
                float4 v3 = x4[(size_t)(i + 6) * 32 + q];
                float d0 = v0.x*cv.x + v0.y*cv.y + v0.z*cv.z + v0.w*cv.w;
                float d1 = v1.x*cv.x + v1.y*cv.y + v1.z*cv.z + v1.w*cv.w;
                float d2 = v2.x*cv.x + v2.y*cv.y + v2.z*cv.z + v2.w*cv.w;
                float d3 = v3.x*cv.x + v3.y*cv.y + v3.z*cv.z + v3.w*cv.w;
                d0 += __shfl_xor(d0,16,64); d1 += __shfl_xor(d1,16,64);
                d2 += __shfl_xor(d2,16,64); d3 += __shfl_xor(d3,16,64);
                d0 += __shfl_xor(d0, 8,64); d1 += __shfl_xor(d1, 8,64);
                d2 += __shfl_xor(d2, 8,64); d3 += __shfl_xor(d3, 8,64);
                d0 += __shfl_xor(d0, 4,64); d1 += __shfl_xor(d1, 4,64);
                d2 += __shfl_xor(d2, 4,64); d3 += __shfl_xor(d3, 4,64);
                d0 += __shfl_xor(d0, 2,64); d1 += __shfl_xor(d1, 2,64);
                d2 += __shfl_xor(d2, 2,64); d3 += __shfl_xor(d3, 2,64);
                d0 += __shfl_xor(d0, 1,64); d1 += __shfl_xor(d1, 1,64);
                d2 += __shfl_xor(d2, 1,64); d3 += __shfl_xor(d3, 1,64);
                const float g0 = 1.0f / (1.0f + __expf(-d0));
                const float g1 = 1.0f / (1.0f + __expf(-d1));
                const float g2 = 1.0f / (1.0f + __expf(-d2));
                const float g3 = 1.0f / (1.0f + __expf(-d3));
                h0.x = fmaf(g0, v0.x, h0.x); h0.y = fmaf(g0, v0.y, h0.y);
                h0.z = fmaf(g0, v0.z, h0.z); h0.w = fmaf(g0, v0.w, h0.w);
                h1.x = fmaf(g1, v1.x, h1.x); h1.y = fmaf(g1, v1.y, h1.y);
                h1.z = fmaf(g1, v1.z, h1.z); h1.w = fmaf(g1, v1.w, h1.w);
                h2.x = fmaf(g2, v2.x, h2.x); h2.y = fmaf(g2, v2.y, h2.y);
                h2.z = fmaf(g2, v2.z, h2.z); h2.w = fmaf(g2, v2.w, h2.w);
                h3.x = fmaf(g3, v3.x, h3.x); h3.y = fmaf(g3, v3.y, h3.y);
                h3.z = fmaf(g3, v3.z, h3.z); h3.w = fmaf(g3, v3.w, h3.w);
            }
            for (; i < e; i += 2) {
                float4 v = x4[(size_t)i * 32 + q];
                float d = v.x*cv.x + v.y*cv.y + v.z*cv.z + v.w*cv.w;
                d += __shfl_xor(d,16,64);
                d += __shfl_xor(d, 8,64);
                d += __shfl_xor(d, 4,64);
                d += __shfl_xor(d, 2,64);
                d += __shfl_xor(d, 1,64);
                const float g = 1.0f / (1.0f + __expf(-d));
                h0.x = fmaf(g, v.x, h0.x); h0.y = fmaf(g, v.y, h0.y);
                h0.z = fmaf(g, v.z, h0.z); h0.w = fmaf(g, v.w, h0.w);
            }
            float4 hacc = f4add(f4add(h0, h1), f4add(h2, h3));
            hacc = f4add(hacc, f4shfl_xor(hacc, 32));
            if (lane < 32)
                ((float4*)out)[(size_t)b * 32 + q] = hacc;
        }
    }
}

extern "C" void kernel_launch(void* const* d_in, const int* in_sizes, int n_in,
                              void* d_out, int out_size, void* d_ws, size_t ws_size,
                              hipStream_t stream) {
    const float* x     = (const float*)d_in[0];
    const float* W     = (const float*)d_in[1];
    const int*   batch = (const int*)d_in[2];
    float*       out   = (float*)d_out;

    const int N = in_sizes[0] / C;   // 2,000,000
    const int B = out_size / C;      // 50,000

    const int grid       = 512;                 // 2 blocks/CU resident
    const int totalWaves = grid * WPB;          // 8192 waves, ~6 contiguous segments each
    hipLaunchKernelGGL(cba_wave_kernel, dim3(grid), dim3(BLK), 0, stream,
                       x, W, batch, out, N, B, totalWaves);
}

// Round 4
// 462.292 us; speedup vs baseline: 2.0125x; 2.0125x over previous
//
#include <hip/hip_runtime.h>
#include <math.h>

#define C       128
#define BLK     256
#define WPB     (BLK / 64)   // 4 waves per block
#define MAXSLOT 32           // 64 rows register-staged per segment (2 rows/slot)

__device__ __forceinline__ float4 f4add(float4 a, float4 b) {
    float4 r; r.x = a.x + b.x; r.y = a.y + b.y; r.z = a.z + b.z; r.w = a.w + b.w; return r;
}
__device__ __forceinline__ float4 f4shfl_xor(float4 v, int m) {
    float4 r;
    r.x = __shfl_xor(v.x, m, 64);
    r.y = __shfl_xor(v.y, m, 64);
    r.z = __shfl_xor(v.z, m, 64);
    r.w = __shfl_xor(v.w, m, 64);
    return r;
}
__device__ __forceinline__ float fast_tanh(float v) {
    // tanh(v) = 1 - 2/(e^{2v}+1); inf-safe both directions
    const float t = __expf(2.0f * v);
    return 1.0f - 2.0f / (t + 1.0f);
}
__device__ __forceinline__ float fast_sigmoid(float v) {
    return 1.0f / (1.0f + __expf(-v));
}
// reduce d across the 32 lanes of this half (xor masks < 32 stay in-half)
__device__ __forceinline__ float half_reduce(float d) {
    d += __shfl_xor(d, 16, 64);
    d += __shfl_xor(d,  8, 64);
    d += __shfl_xor(d,  4, 64);
    d += __shfl_xor(d,  2, 64);
    d += __shfl_xor(d,  1, 64);
    return d;
}

extern "C" __global__ __launch_bounds__(BLK)
void cba_reg_kernel(const float* __restrict__ x,
                    const float* __restrict__ W,
                    const int* __restrict__ batch,
                    float* __restrict__ out,
                    int N, int B, int totalWaves)
{
    __shared__ float4 sW4[C * C / 4];   // 64 KB; 2 blocks/CU -> 128 KB of 160 KB

    const int t    = threadIdx.x;
    const int lane = t & 63;
    const int q    = lane & 31;   // owns channels/cols 4q..4q+3
    const int h    = lane >> 5;   // half 0/1

    // ---- one-time: W into LDS ----
    const float4* Wg = (const float4*)W;
#pragma unroll
    for (int i = 0; i < (C * C / 4) / BLK; ++i)       // 16 iters
        sW4[t + i * BLK] = Wg[t + i * BLK];
    __syncthreads();

    const int gw = blockIdx.x * WPB + (t >> 6);       // global wave id, 0..2047

    // ---- chunk-contiguous segment assignment ----
    const int qn = B / totalWaves;
    const int r  = B % totalWaves;
    const int segStart = gw * qn + (gw < r ? gw : r);
    const int myCnt    = qn + (gw < r ? 1 : 0);       // <= 25

    // ---- lane-parallel boundary search: lane l -> start of segment segStart+min(l,myCnt) ----
    const int tl     = lane < myCnt ? lane : myCnt;
    const int target = segStart + tl;
    int lo = 0, hi = N;
    while (lo < hi) {
        int mid = (lo + hi) >> 1;
        if (batch[mid] < target) lo = mid + 1; else hi = mid;
    }
    const int bs = lo;
    const float4* x4 = (const float4*)x;

    for (int k = 0; k < myCnt; ++k) {
        const int b   = segStart + k;
        const int s   = __shfl(bs, k, 64);
        const int e   = __shfl(bs, k + 1, 64);
        const int cnt = e - s;

        // ======== stage up to 64 rows into registers (32 independent 16B loads) ========
        float4 rb[MAXSLOT];
#pragma unroll
        for (int sl = 0; sl < MAXSLOT; ++sl) {
            const int row = s + 2 * sl + h;
            rb[sl] = make_float4(0.f, 0.f, 0.f, 0.f);
            if (row < e) rb[sl] = x4[(size_t)row * 32 + q];
        }

        // ======== pass 1: channel sums (registers + rare global tail) ========
        float4 s0 = make_float4(0.f,0.f,0.f,0.f), s1 = s0, s2 = s0, s3 = s0;
#pragma unroll
        for (int g4 = 0; g4 < MAXSLOT / 4; ++g4) {
            s0 = f4add(s0, rb[4 * g4 + 0]);
            s1 = f4add(s1, rb[4 * g4 + 1]);
            s2 = f4add(s2, rb[4 * g4 + 2]);
            s3 = f4add(s3, rb[4 * g4 + 3]);
        }
        float4 acc = f4add(f4add(s0, s1), f4add(s2, s3));
        for (int i = s + 2 * MAXSLOT + h; i < e; i += 2)      // tail rows >64 (rare)
            acc = f4add(acc, x4[(size_t)i * 32 + q]);
        acc = f4add(acc, f4shfl_xor(acc, 32));
        const float inv = 1.0f / (float)(cnt > 0 ? cnt : 1);
        float4 mean;
        mean.x = acc.x * inv; mean.y = acc.y * inv;
        mean.z = acc.z * inv; mean.w = acc.w * inv;

        // ======== GEMM: c = tanh(mean @ W), split-K across halves ========
        float4 p = make_float4(0.f,0.f,0.f,0.f);
#pragma unroll
        for (int j = 0; j < 16; ++j) {
            const int src = (h << 4) + j;
            const float mx = __shfl(mean.x, src, 64);
            const float my = __shfl(mean.y, src, 64);
            const float mz = __shfl(mean.z, src, 64);
            const float mw = __shfl(mean.w, src, 64);
            const int k0 = (h << 6) + (j << 2);
            const float4 w0 = sW4[(k0 + 0) * 32 + q];
            const float4 w1 = sW4[(k0 + 1) * 32 + q];
            const float4 w2 = sW4[(k0 + 2) * 32 + q];
            const float4 w3 = sW4[(k0 + 3) * 32 + q];
            p.x = fmaf(mx, w0.x, p.x); p.y = fmaf(mx, w0.y, p.y);
            p.z = fmaf(mx, w0.z, p.z); p.w = fmaf(mx, w0.w, p.w);
            p.x = fmaf(my, w1.x, p.x); p.y = fmaf(my, w1.y, p.y);
            p.z = fmaf(my, w1.z, p.z); p.w = fmaf(my, w1.w, p.w);
            p.x = fmaf(mz, w2.x, p.x); p.y = fmaf(mz, w2.y, p.y);
            p.z = fmaf(mz, w2.z, p.z); p.w = fmaf(mz, w2.w, p.w);
            p.x = fmaf(mw, w3.x, p.x); p.y = fmaf(mw, w3.y, p.y);
            p.z = fmaf(mw, w3.z, p.z); p.w = fmaf(mw, w3.w, p.w);
        }
        p = f4add(p, f4shfl_xor(p, 32));
        float4 cv;
        cv.x = fast_tanh(p.x); cv.y = fast_tanh(p.y);
        cv.z = fast_tanh(p.z); cv.w = fast_tanh(p.w);

        // ======== pass 2: gates + h from REGISTERS (zero extra HBM traffic) ========
        // masked-out slots hold rb=0 -> g*0 contributes nothing; no predication needed
        float4 h0 = make_float4(0.f,0.f,0.f,0.f), h1 = h0, h2 = h0, h3 = h0;
#pragma unroll
        for (int g4 = 0; g4 < MAXSLOT / 4; ++g4) {
            const float4 v0 = rb[4 * g4 + 0];
            const float4 v1 = rb[4 * g4 + 1];
            const float4 v2 = rb[4 * g4 + 2];
            const float4 v3 = rb[4 * g4 + 3];
            float d0 = v0.x*cv.x + v0.y*cv.y + v0.z*cv.z + v0.w*cv.w;
            float d1 = v1.x*cv.x + v1.y*cv.y + v1.z*cv.z + v1.w*cv.w;
            float d2 = v2.x*cv.x + v2.y*cv.y + v2.z*cv.z + v2.w*cv.w;
            float d3 = v3.x*cv.x + v3.y*cv.y + v3.z*cv.z + v3.w*cv.w;
            d0 += __shfl_xor(d0,16,64); d1 += __shfl_xor(d1,16,64);
            d2 += __shfl_xor(d2,16,64); d3 += __shfl_xor(d3,16,64);
            d0 += __shfl_xor(d0, 8,64); d1 += __shfl_xor(d1, 8,64);
            d2 += __shfl_xor(d2, 8,64); d3 += __shfl_xor(d3, 8,64);
            d0 += __shfl_xor(d0, 4,64); d1 += __shfl_xor(d1, 4,64);
            d2 += __shfl_xor(d2, 4,64); d3 += __shfl_xor(d3, 4,64);
            d0 += __shfl_xor(d0, 2,64); d1 += __shfl_xor(d1, 2,64);
            d2 += __shfl_xor(d2, 2,64); d3 += __shfl_xor(d3, 2,64);
            d0 += __shfl_xor(d0, 1,64); d1 += __shfl_xor(d1, 1,64);
            d2 += __shfl_xor(d2, 1,64); d3 += __shfl_xor(d3, 1,64);
            const float g0 = fast_sigmoid(d0);
            const float g1 = fast_sigmoid(d1);
            const float g2 = fast_sigmoid(d2);
            const float g3 = fast_sigmoid(d3);
            h0.x = fmaf(g0, v0.x, h0.x); h0.y = fmaf(g0, v0.y, h0.y);
            h0.z = fmaf(g0, v0.z, h0.z); h0.w = fmaf(g0, v0.w, h0.w);
            h1.x = fmaf(g1, v1.x, h1.x); h1.y = fmaf(g1, v1.y, h1.y);
            h1.z = fmaf(g1, v1.z, h1.z); h1.w = fmaf(g1, v1.w, h1.w);
            h2.x = fmaf(g2, v2.x, h2.x); h2.y = fmaf(g2, v2.y, h2.y);
            h2.z = fmaf(g2, v2.z, h2.z); h2.w = fmaf(g2, v2.w, h2.w);
            h3.x = fmaf(g3, v3.x, h3.x); h3.y = fmaf(g3, v3.y, h3.y);
            h3.z = fmaf(g3, v3.z, h3.z); h3.w = fmaf(g3, v3.w, h3.w);
        }
        // rare tail rows >64: re-read from global (L2-hot)
        for (int i = s + 2 * MAXSLOT + h; i < e; i += 2) {
            const float4 v = x4[(size_t)i * 32 + q];
            float d = v.x*cv.x + v.y*cv.y + v.z*cv.z + v.w*cv.w;
            d = half_reduce(d);
            const float g = fast_sigmoid(d);
            h0.x = fmaf(g, v.x, h0.x); h0.y = fmaf(g, v.y, h0.y);
            h0.z = fmaf(g, v.z, h0.z); h0.w = fmaf(g, v.w, h0.w);
        }
        float4 hacc = f4add(f4add(h0, h1), f4add(h2, h3));
        hacc = f4add(hacc, f4shfl_xor(hacc, 32));
        if (lane < 32)
            ((float4*)out)[(size_t)b * 32 + q] = hacc;
    }
}

extern "C" void kernel_launch(void* const* d_in, const int* in_sizes, int n_in,
                              void* d_out, int out_size, void* d_ws, size_t ws_size,
                              hipStream_t stream) {
    const float* x     = (const float*)d_in[0];
    const float* W     = (const float*)d_in[1];
    const int*   batch = (const int*)d_in[2];
    float*       out   = (float*)d_out;

    const int N = in_sizes[0] / C;   // 2,000,000
    const int B = out_size / C;      // 50,000

    const int grid       = 512;                 // 512 blocks x 4 waves = 2048 waves, all resident at 8 waves/CU
    const int totalWaves = grid * WPB;
    hipLaunchKernelGGL(cba_reg_kernel, dim3(grid), dim3(BLK), 0, stream,
                       x, W, batch, out, N, B, totalWaves);
}